// Round 2
// baseline (4551.203 us; speedup 1.0000x reference)
//
#include <hip/hip_runtime.h>
#include <hip/hip_bf16.h>
#include <cstdint>
#include <cstddef>

// ---------------------------------------------------------------------------
// AudioEncoder (Whisper-style) forward for MI355X.
// B=8, T=4096, n_mels=128, D=1024, H=8 heads (hd=128), F=4096, L=6, S=1024.
// All matmul-shaped work runs through one bf16 MFMA GEMM (m97 structure).
// Workspace budget ~126 MB: per-layer weight conversion, 2-batch attention
// passes, F/2 MLP passes, heavy buffer aliasing; f32 carry lives in d_out.
// ---------------------------------------------------------------------------

typedef __bf16 bf16_t;
typedef __bf16 bf16x8 __attribute__((ext_vector_type(8)));
typedef __bf16 bf16x4 __attribute__((ext_vector_type(4)));
typedef __bf16 bf16x2 __attribute__((ext_vector_type(2)));
typedef float  floatx4 __attribute__((ext_vector_type(4)));

#define NB   8
#define NS   1024
#define ND   1024
#define NH   8
#define NHD  128
#define NF   4096
#define NT   4096
#define NT1  2048

__device__ __forceinline__ float gelu_f(float x) {
  return 0.5f * x * (1.0f + erff(x * 0.70710678118654752440f));
}

__device__ __forceinline__ void gload16(const void* g, void* l) {
  // async global->LDS, 16B per lane; LDS dest = wave-uniform base + lane*16
  __builtin_amdgcn_global_load_lds(
      (__attribute__((address_space(1))) void*)(const_cast<void*>(g)),
      (__attribute__((address_space(3))) void*)l, 16, 0, 0);
}

enum { EPI_BF16 = 0, EPI_VT = 1, EPI_GELU_BF16 = 2, EPI_GELU_F32 = 3, EPI_RES_F32 = 4 };

// C = A (M,K) @ B^T where B is stored (N,K) row-major.  128x128 tile, 4 waves,
// each wave computes a 64x64 quadrant as 4x4 frags of 16x16x32 bf16 MFMA.
// Batched via blockIdx.z: off = (z/bMod)*Hi + (z%bMod)*Lo for A,B,C.
template<int EPI>
__global__ __launch_bounds__(256)
void gemm_bt(const bf16_t* __restrict__ A, long lda, long aHi, long aLo,
             const bf16_t* __restrict__ Bm, long ldb, long bHi, long bLo,
             void* Cv, long ldc, long cHi, long cLo,
             const float* __restrict__ bias, const float* res,
             int K, int bMod)
{
  __shared__ bf16_t sA[128 * 32];
  __shared__ bf16_t sB[128 * 32];
  const int tid  = threadIdx.x;
  const int w    = tid >> 6;
  const int lane = tid & 63;
  const int z  = blockIdx.z;
  const int zq = z / bMod, zr = z % bMod;
  const bf16_t* Ab = A  + (long)zq * aHi + (long)zr * aLo;
  const bf16_t* Bb = Bm + (long)zq * bHi + (long)zr * bLo;
  const long offC  = (long)zq * cHi + (long)zr * cLo;
  const int m0 = blockIdx.x * 128, n0 = blockIdx.y * 128;

  const int lrow = lane >> 2;        // 0..15
  const int lcol = (lane & 3) * 8;   // 0,8,16,24 (elems)
  const int seg0 = w * 2;

  floatx4 acc[4][4] = {};
  const int wr = w >> 1, wc = w & 1;

  for (int kb = 0; kb < K; kb += 32) {
#pragma unroll
    for (int j = 0; j < 2; ++j) {
      const int seg = seg0 + j;      // 0..7, 1024B LDS segment per call
      gload16(Ab + (long)(m0 + seg * 16 + lrow) * lda + (kb + lcol), &sA[seg * 512]);
      gload16(Bb + (long)(n0 + seg * 16 + lrow) * ldb + (kb + lcol), &sB[seg * 512]);
    }
    __syncthreads();
    bf16x8 av[4], bv[4];
#pragma unroll
    for (int i = 0; i < 4; ++i) {
      av[i] = *reinterpret_cast<const bf16x8*>(
          &sA[(wr * 64 + i * 16 + (lane & 15)) * 32 + (lane >> 4) * 8]);
      bv[i] = *reinterpret_cast<const bf16x8*>(
          &sB[(wc * 64 + i * 16 + (lane & 15)) * 32 + (lane >> 4) * 8]);
    }
#pragma unroll
    for (int mi = 0; mi < 4; ++mi)
#pragma unroll
      for (int ni = 0; ni < 4; ++ni)
        acc[mi][ni] = __builtin_amdgcn_mfma_f32_16x16x32_bf16(av[mi], bv[ni], acc[mi][ni], 0, 0, 0);
    __syncthreads();
  }

#pragma unroll
  for (int ni = 0; ni < 4; ++ni) {
    const int col = n0 + wc * 64 + ni * 16 + (lane & 15);
    const float bvs = bias ? bias[col] : 0.0f;
#pragma unroll
    for (int mi = 0; mi < 4; ++mi) {
#pragma unroll
      for (int r = 0; r < 4; ++r) {
        const int row = m0 + wr * 64 + mi * 16 + (lane >> 4) * 4 + r;
        float v = acc[mi][ni][r] + bvs;
        if constexpr (EPI == EPI_BF16) {
          ((bf16_t*)Cv)[offC + (long)row * ldc + col] = (bf16_t)v;
        } else if constexpr (EPI == EPI_VT) {
          // v-proj: row=(b*1024+s), col=(h*128+d) -> vt[b][h][d][s]
          ((bf16_t*)Cv)[(long)(row >> 10) * cHi + (long)col * ldc + (row & 1023)] = (bf16_t)v;
        } else if constexpr (EPI == EPI_GELU_BF16) {
          ((bf16_t*)Cv)[offC + (long)row * ldc + col] = (bf16_t)gelu_f(v);
        } else if constexpr (EPI == EPI_GELU_F32) {
          ((float*)Cv)[offC + (long)row * ldc + col] = gelu_f(v);
        } else {  // EPI_RES_F32
          const long idx = offC + (long)row * ldc + col;
          ((float*)Cv)[idx] = res[idx] + v;
        }
      }
    }
  }
}

// LayerNorm: one block per row of 1024 f32 -> bf16
__global__ __launch_bounds__(256)
void ln_kernel(const float* __restrict__ x, bf16_t* __restrict__ y,
               const float* __restrict__ w, const float* __restrict__ b)
{
  const long row = blockIdx.x;
  const float4 v = reinterpret_cast<const float4*>(x + row * ND)[threadIdx.x];
  float s  = v.x + v.y + v.z + v.w;
  float ss = v.x * v.x + v.y * v.y + v.z * v.z + v.w * v.w;
#pragma unroll
  for (int off = 32; off; off >>= 1) { s += __shfl_down(s, off); ss += __shfl_down(ss, off); }
  __shared__ float sh[8];
  if ((threadIdx.x & 63) == 0) { sh[threadIdx.x >> 6] = s; sh[4 + (threadIdx.x >> 6)] = ss; }
  __syncthreads();
  const float tot  = sh[0] + sh[1] + sh[2] + sh[3];
  const float tot2 = sh[4] + sh[5] + sh[6] + sh[7];
  const float mean = tot * (1.0f / ND);
  const float var  = tot2 * (1.0f / ND) - mean * mean;
  const float rstd = rsqrtf(var + 1e-5f);
  const int i0 = threadIdx.x * 4;
  const float vv[4] = {v.x, v.y, v.z, v.w};
  bf16x4 o;
#pragma unroll
  for (int j = 0; j < 4; ++j)
    o[j] = (bf16_t)((vv[j] - mean) * rstd * w[i0 + j] + b[i0 + j]);
  reinterpret_cast<bf16x4*>(y + row * ND)[threadIdx.x] = o;
}

// masked softmax over one score row (1024), in place, bf16.
// p covers 2 batches: row = (b_rel*8 + h)*1024 + q; validb = valid + b0*1024.
__global__ __launch_bounds__(256)
void softmax_kernel(bf16_t* __restrict__ p, const float* __restrict__ validb)
{
  const long row = blockIdx.x;
  const int b_rel = (int)(row >> 13);
  bf16_t* pr = p + row * (long)NS;
  const float* vb = validb + (long)b_rel * NS;
  const int i0 = threadIdx.x * 4;
  bf16x4 raw = reinterpret_cast<const bf16x4*>(pr)[threadIdx.x];
  float sv[4]; float mx = -3e38f;
#pragma unroll
  for (int j = 0; j < 4; ++j) {
    float s = (vb[i0 + j] != 0.0f) ? (float)raw[j] : -3e38f;
    sv[j] = s; mx = fmaxf(mx, s);
  }
#pragma unroll
  for (int off = 32; off; off >>= 1) mx = fmaxf(mx, __shfl_down(mx, off));
  __shared__ float sh[4];
  if ((threadIdx.x & 63) == 0) sh[threadIdx.x >> 6] = mx;
  __syncthreads();
  mx = fmaxf(fmaxf(sh[0], sh[1]), fmaxf(sh[2], sh[3]));
  __syncthreads();
  float sum = 0.0f;
#pragma unroll
  for (int j = 0; j < 4; ++j) {
    float e = (sv[j] > -1e37f) ? __expf(sv[j] - mx) : 0.0f;
    sv[j] = e; sum += e;
  }
#pragma unroll
  for (int off = 32; off; off >>= 1) sum += __shfl_down(sum, off);
  if ((threadIdx.x & 63) == 0) sh[threadIdx.x >> 6] = sum;
  __syncthreads();
  sum = sh[0] + sh[1] + sh[2] + sh[3];
  const float inv = 1.0f / sum;
  bf16x4 o;
#pragma unroll
  for (int j = 0; j < 4; ++j) o[j] = (bf16_t)(sv[j] * inv);
  reinterpret_cast<bf16x4*>(pr)[threadIdx.x] = o;
}

// interleaved RoPE + hd^-0.25 scale, in place on (B,S,H,hd) bf16
__global__ __launch_bounds__(256)
void rope_kernel(bf16_t* __restrict__ t)
{
  const long idx = (long)blockIdx.x * 256 + threadIdx.x;  // B*S*H*64 pairs
  const int  i  = (int)(idx & 63);
  const int  h  = (int)((idx >> 6) & 7);
  const long bs = idx >> 9;                               // b*1024+s
  const int  s  = (int)(bs & 1023);
  const float freq = __expf((float)(2 * i) * (-9.210340371976184f / 128.0f)); // 10000^(-2i/128)
  float sn, cs;
  sincosf((float)s * freq, &sn, &cs);
  const long base = bs * ND + (long)h * NHD + 2 * i;
  bf16x2 v = *reinterpret_cast<bf16x2*>(t + base);
  const float re = (float)v[0], im = (float)v[1];
  const float sc = 0.29730177875068026f;                  // 128^(-0.25)
  bf16x2 o;
  o[0] = (bf16_t)((re * cs - im * sn) * sc);
  o[1] = (bf16_t)((re * sn + im * cs) * sc);
  *reinterpret_cast<bf16x2*>(t + base) = o;
}

// im2col for conv1: A1[(b*2048+t), i*3+kk] = x[b, i, 2t+kk-1] (pad 1), f32->bf16
__global__ __launch_bounds__(256)
void im2col1_kernel(const float* __restrict__ x, bf16_t* __restrict__ a)
{
  const long idx = (long)blockIdx.x * 256 + threadIdx.x;
  if (idx >= (long)NB * NT1 * 384) return;
  const int  k = (int)(idx % 384);
  const long m = idx / 384;
  const int i = k / 3, kk = k - 3 * i;
  const int t = (int)(m & (NT1 - 1));
  const int b = (int)(m >> 11);
  const int tt = 2 * t + kk - 1;
  float v = 0.0f;
  if (tt >= 0 && tt < NT) v = x[((long)b * 128 + i) * NT + tt];
  a[idx] = (bf16_t)v;
}

// im2col for conv2: A2[(b*1024+t), i*3+kk] = h1[b, 2t+kk-1, i] (pad 1)
__global__ __launch_bounds__(256)
void im2col2_kernel(const bf16_t* __restrict__ h1, bf16_t* __restrict__ a)
{
  const long idx = (long)blockIdx.x * 256 + threadIdx.x;
  if (idx >= (long)NB * NS * 3072) return;
  const int  k = (int)(idx % 3072);
  const long m = idx / 3072;
  const int i = k / 3, kk = k - 3 * i;
  const int t = (int)(m & (NS - 1));
  const int b = (int)(m >> 10);
  const int tt = 2 * t + kk - 1;
  bf16_t v = (bf16_t)0.0f;
  if (tt >= 0 && tt < NT1) v = h1[((long)b * NT1 + tt) * ND + i];
  a[idx] = v;
}

// valid[b,j] = (4j+3 < x_len[b])
__global__ __launch_bounds__(256)
void mask_kernel(const int* __restrict__ xlen, float* __restrict__ valid)
{
  const int idx = blockIdx.x * 256 + threadIdx.x;
  if (idx >= NB * NS) return;
  const int b = idx >> 10, j = idx & 1023;
  valid[idx] = (4 * j + 3 < xlen[b]) ? 1.0f : 0.0f;
}

// y_len = ((x_len+1)//2 + 1)//2 as float; launched LAST so nothing clobbers it
__global__ void ylen_kernel(const int* __restrict__ xlen, float* __restrict__ ylen)
{
  const int b = threadIdx.x;
  if (b < NB) {
    const int y1 = (xlen[b] + 1) >> 1;
    ylen[b] = (float)((y1 + 1) >> 1);
  }
}

__global__ __launch_bounds__(256)
void cvt_kernel(const float* __restrict__ in, bf16_t* __restrict__ out, long n)
{
  const long i = ((long)blockIdx.x * 256 + threadIdx.x) * 4;
  if (i >= n) return;
  const float4 v = *reinterpret_cast<const float4*>(in + i);
  bf16x4 o;
  o[0] = (bf16_t)v.x; o[1] = (bf16_t)v.y; o[2] = (bf16_t)v.z; o[3] = (bf16_t)v.w;
  *reinterpret_cast<bf16x4*>(out + i) = o;
}

extern "C" void kernel_launch(void* const* d_in, const int* in_sizes, int n_in,
                              void* d_out, int out_size, void* d_ws, size_t ws_size,
                              hipStream_t stream)
{
  const float* x         = (const float*)d_in[0];
  const int*   x_len     = (const int*)  d_in[1];
  const float* conv1_w   = (const float*)d_in[2];
  const float* conv1_b   = (const float*)d_in[3];
  const float* conv2_w   = (const float*)d_in[4];
  const float* conv2_b   = (const float*)d_in[5];
  const float* attn_ln_w = (const float*)d_in[6];
  const float* attn_ln_b = (const float*)d_in[7];
  const float* q_w   = (const float*)d_in[8];
  const float* q_b   = (const float*)d_in[9];
  const float* k_w   = (const float*)d_in[10];
  const float* v_w   = (const float*)d_in[11];
  const float* v_b   = (const float*)d_in[12];
  const float* out_w = (const float*)d_in[13];
  const float* out_b = (const float*)d_in[14];
  const float* mlp_ln_w = (const float*)d_in[15];
  const float* mlp_ln_b = (const float*)d_in[16];
  const float* mlp1_w = (const float*)d_in[17];
  const float* mlp1_b = (const float*)d_in[18];
  const float* mlp2_w = (const float*)d_in[19];
  const float* mlp2_b = (const float*)d_in[20];
  float* outp = (float*)d_out;
  (void)in_sizes; (void)n_in; (void)out_size;

  // ---- workspace layout (~126 MB), contiguous (all sizes 256-multiples) ----
  char* ws = (char*)d_ws;
  size_t off = 0;
  auto alloc = [&](size_t bytes) -> char* {
    char* p = ws + off;
    off += (bytes + 255) & ~(size_t)255;
    return p;
  };
  float*  valid = (float*) alloc(NB * NS * 4);            //  32 KB
  bf16_t* ybuf  = (bf16_t*)alloc(8L * 1024 * 1024 * 2);   //  16 MB | a1 (conv)
  bf16_t* qbuf  = (bf16_t*)alloc(8L * 1024 * 1024 * 2);   //  16 MB | h1[0:16] ; obuf (attn)
  bf16_t* kbuf  = (bf16_t*)alloc(8L * 1024 * 1024 * 2);   //  16 MB | h1[16:32]
  bf16_t* vt    = (bf16_t*)alloc(8L * 1024 * 1024 * 2);   //  16 MB | a2[0:16]
  bf16_t* wq    = (bf16_t*)alloc(1024L * 1024 * 2);       //   2 MB | a2
  bf16_t* wk    = (bf16_t*)alloc(1024L * 1024 * 2);       //   2 MB | a2
  bf16_t* wv    = (bf16_t*)alloc(1024L * 1024 * 2);       //   2 MB | a2
  bf16_t* wo    = (bf16_t*)alloc(1024L * 1024 * 2);       //   2 MB | a2
  bf16_t* w1b   = (bf16_t*)alloc(4096L * 1024 * 2);       //   8 MB | a2[24:32]
  bf16_t* w2b   = (bf16_t*)alloc(4096L * 1024 * 2);       //   8 MB | a2[32:40]
  char*   arena = alloc(32L * 1024 * 1024);               //  32 MB | a2[40:48]+c2w+c1w | scb | hid
  const size_t required = off;                            // ~125.9 MB

  // conv-phase aliases
  bf16_t* a1  = ybuf;                                     // 12 MB
  bf16_t* h1  = qbuf;                                     // 32 MB (qbuf+kbuf)
  bf16_t* a2  = vt;                                       // 48 MB (vt..arena+8MB)
  bf16_t* c2w = (bf16_t*)(arena + 8L * 1024 * 1024);      //  6 MB
  bf16_t* c1w = (bf16_t*)(arena + 16L * 1024 * 1024);     // 0.75 MB
  // loop-phase aliases
  bf16_t* scb  = (bf16_t*)arena;                          // 32 MB (2-batch scores)
  bf16_t* hid  = (bf16_t*)arena;                          // 32 MB (8192 x 2048)
  bf16_t* obuf = qbuf;

  if (required > ws_size || ws_size < NB * NS * 4) {
    // degraded: at least make y_len exact (needs no scratch)
    ylen_kernel<<<dim3(1), 64, 0, stream>>>(x_len, outp + 8L * 1024 * 1024);
    return;
  }

  auto cvt = [&](const float* in, bf16_t* o, long n) {
    cvt_kernel<<<dim3((unsigned)(n / 1024)), 256, 0, stream>>>(in, o, n);
  };

  mask_kernel<<<dim3(32), 256, 0, stream>>>(x_len, valid);

  // ---- conv stem ----
  cvt(conv1_w, c1w, 1024L * 384);
  cvt(conv2_w, c2w, 1024L * 3072);
  im2col1_kernel<<<dim3((unsigned)((16384L * 384) / 256)), 256, 0, stream>>>(x, a1);
  gemm_bt<EPI_GELU_BF16><<<dim3(128, 8, 1), 256, 0, stream>>>(
      a1, 384, 0, 0, c1w, 384, 0, 0, h1, 1024, 0, 0, conv1_b, nullptr, 384, 1);
  im2col2_kernel<<<dim3((unsigned)((8192L * 3072) / 256)), 256, 0, stream>>>(h1, a2);
  gemm_bt<EPI_GELU_F32><<<dim3(64, 8, 1), 256, 0, stream>>>(
      a2, 3072, 0, 0, c2w, 3072, 0, 0, outp /*carry*/, 1024, 0, 0, conv2_b, nullptr, 3072, 1);

  float* carry = outp;  // f32 residual stream lives in d_out

  for (int l = 0; l < 6; ++l) {
    cvt(q_w   + (long)l * 1048576, wq,  1048576);
    cvt(k_w   + (long)l * 1048576, wk,  1048576);
    cvt(v_w   + (long)l * 1048576, wv,  1048576);
    cvt(out_w + (long)l * 1048576, wo,  1048576);
    cvt(mlp1_w + (long)l * 4194304, w1b, 4194304);
    cvt(mlp2_w + (long)l * 4194304, w2b, 4194304);

    ln_kernel<<<dim3(8192), 256, 0, stream>>>(carry, ybuf, attn_ln_w + l * 1024, attn_ln_b + l * 1024);

    gemm_bt<EPI_BF16><<<dim3(64, 8, 1), 256, 0, stream>>>(
        ybuf, 1024, 0, 0, wq, 1024, 0, 0, qbuf, 1024, 0, 0, q_b + l * 1024, nullptr, 1024, 1);
    gemm_bt<EPI_BF16><<<dim3(64, 8, 1), 256, 0, stream>>>(
        ybuf, 1024, 0, 0, wk, 1024, 0, 0, kbuf, 1024, 0, 0, nullptr, nullptr, 1024, 1);
    gemm_bt<EPI_VT><<<dim3(64, 8, 1), 256, 0, stream>>>(
        ybuf, 1024, 0, 0, wv, 1024, 0, 0, vt, 1024, 1048576, 0, v_b + l * 1024, nullptr, 1024, 1);

    rope_kernel<<<dim3(16384), 256, 0, stream>>>(qbuf);
    rope_kernel<<<dim3(16384), 256, 0, stream>>>(kbuf);

    // attention, 2 batches per pass (scores fit in 32 MB arena)
    for (int b0 = 0; b0 < NB; b0 += 2) {
      // scb[b_rel,h] = q_head @ k_head^T   (M=N=1024, K=128)
      gemm_bt<EPI_BF16><<<dim3(8, 8, 16), 256, 0, stream>>>(
          qbuf + (long)b0 * 1048576, 1024, 1048576, 128,
          kbuf + (long)b0 * 1048576, 1024, 1048576, 128,
          scb, 1024, 8388608, 1048576, nullptr, nullptr, 128, 8);
      softmax_kernel<<<dim3(16384), 256, 0, stream>>>(scb, valid + (long)b0 * NS);
      // obuf[b,s,h*128+d] = P @ V  (vt rows are d)  (M=1024, N=128, K=1024)
      gemm_bt<EPI_BF16><<<dim3(8, 1, 16), 256, 0, stream>>>(
          scb, 1024, 8388608, 1048576,
          vt + (long)b0 * 1048576, 1024, 1048576, 131072,
          obuf + (long)b0 * 1048576, 1024, 1048576, 128, nullptr, nullptr, 1024, 8);
    }

    // carry += o @ ow^T + ob
    gemm_bt<EPI_RES_F32><<<dim3(64, 8, 1), 256, 0, stream>>>(
        obuf, 1024, 0, 0, wo, 1024, 0, 0, carry, 1024, 0, 0, out_b + l * 1024, carry, 1024, 1);

    ln_kernel<<<dim3(8192), 256, 0, stream>>>(carry, ybuf, mlp_ln_w + l * 1024, mlp_ln_b + l * 1024);

    // MLP in two F/2 passes (hid = 8192 x 2048 in arena)
    for (int f = 0; f < 2; ++f) {
      gemm_bt<EPI_GELU_BF16><<<dim3(64, 16, 1), 256, 0, stream>>>(
          ybuf, 1024, 0, 0, w1b + (long)f * 2048 * 1024, 1024, 0, 0,
          hid, 2048, 0, 0, mlp1_b + (long)l * 4096 + f * 2048, nullptr, 1024, 1);
      gemm_bt<EPI_RES_F32><<<dim3(64, 8, 1), 256, 0, stream>>>(
          hid, 2048, 0, 0, w2b + (long)f * 2048, 4096, 0, 0,
          carry, 1024, 0, 0, (f == 0) ? (mlp2_b + l * 1024) : nullptr, carry, 2048, 1);
    }
  }

  ylen_kernel<<<dim3(1), 64, 0, stream>>>(x_len, outp + 8L * 1024 * 1024);
}

// Round 3
// 4038.586 us; speedup vs baseline: 1.1269x; 1.1269x over previous
//
#include <hip/hip_runtime.h>
#include <hip/hip_bf16.h>
#include <cstdint>
#include <cstddef>

// ---------------------------------------------------------------------------
// AudioEncoder (Whisper-style) forward for MI355X.
// B=8, T=4096, n_mels=128, D=1024, H=8 heads (hd=128), F=4096, L=6, S=1024.
// bf16 MFMA GEMM (128x128 tile, 4 waves) with 2-phase double-buffered LDS
// pipeline, fused QKV+RoPE epilogue, XCD-swizzled block mapping.
// ---------------------------------------------------------------------------

typedef __bf16 bf16_t;
typedef __bf16 bf16x8 __attribute__((ext_vector_type(8)));
typedef __bf16 bf16x4 __attribute__((ext_vector_type(4)));
typedef float  floatx4 __attribute__((ext_vector_type(4)));

#define NB   8
#define NS   1024
#define ND   1024
#define NT   4096
#define NT1  2048

__device__ __forceinline__ float gelu_f(float x) {
  return 0.5f * x * (1.0f + erff(x * 0.70710678118654752440f));
}

__device__ __forceinline__ void gload16(const void* g, void* l) {
  __builtin_amdgcn_global_load_lds(
      (__attribute__((address_space(1))) void*)(const_cast<void*>(g)),
      (__attribute__((address_space(3))) void*)l, 16, 0, 0);
}

enum { EPI_BF16 = 0, EPI_GELU_BF16 = 2, EPI_GELU_F32 = 3, EPI_RES_F32 = 4, EPI_QKV = 5 };

// C = A (M,K) @ B^T, B stored (N,K) row-major. 128x128 tile, 4 waves, each a
// 64x64 quadrant of 4x4 16x16x32-bf16 MFMA frags. Double-buffered LDS: stage
// tile t+1 before computing tile t; single barrier per K-step.
// Batched via blockIdx.z: off = (z/bMod)*Hi + (z%bMod)*Lo.
// EPI_QKV: grid-y tiles [0,8)=Q -> Cv (rope), [8,16)=K -> out2 (rope),
// [16,24)=V -> out3 transposed (vt[b][h][d][s]); rtab = pre-scaled cos/sin.
template<int EPI>
__global__ __launch_bounds__(256)
void gemm_bt(const bf16_t* __restrict__ A, long lda, long aHi, long aLo,
             const bf16_t* __restrict__ Bm, long ldb, long bHi, long bLo,
             void* Cv, long ldc, long cHi, long cLo,
             const float* __restrict__ bias, const float* res,
             int K, int bMod, int swz,
             bf16_t* out2, bf16_t* out3, const float* __restrict__ bias2,
             const float2* __restrict__ rtab)
{
  __shared__ bf16_t sA[2][128 * 32];
  __shared__ bf16_t sB[2][128 * 32];
  const int tid  = threadIdx.x;
  const int w    = tid >> 6;
  const int lane = tid & 63;
  const int z  = blockIdx.z;
  const int zq = z / bMod, zr = z % bMod;
  const bf16_t* Ab = A  + (long)zq * aHi + (long)zr * aLo;
  const bf16_t* Bb = Bm + (long)zq * bHi + (long)zr * bLo;
  const long offC  = (long)zq * cHi + (long)zr * cLo;

  int bx = blockIdx.x, by = blockIdx.y;
  if (swz) {               // bijective XCD-chunked remap (grid size % 8 == 0)
    const int gx = gridDim.x;
    const int n  = gx * gridDim.y;
    int id = bx + by * gx;
    id = (id & 7) * (n >> 3) + (id >> 3);
    bx = id % gx; by = id / gx;
  }
  const int m0 = bx * 128, n0 = by * 128;

  const int lrow = lane >> 2;        // 0..15
  const int lcol = (lane & 3) * 8;   // elem offset 0,8,16,24
  const int seg0 = w * 2;

  floatx4 acc[4][4] = {};
  const int wr = w >> 1, wc = w & 1;

  auto stage = [&](int kb, int buf) {
#pragma unroll
    for (int j = 0; j < 2; ++j) {
      const int seg = seg0 + j;      // 8 segs x 16 rows
      gload16(Ab + (long)(m0 + seg * 16 + lrow) * lda + (kb + lcol), &sA[buf][seg * 512]);
      gload16(Bb + (long)(n0 + seg * 16 + lrow) * ldb + (kb + lcol), &sB[buf][seg * 512]);
    }
  };

  stage(0, 0);
  __syncthreads();
  int cur = 0;
  for (int kb = 0; kb < K; kb += 32) {
    if (kb + 32 < K) stage(kb + 32, cur ^ 1);   // prefetch overlaps compute
    bf16x8 av[4], bv[4];
#pragma unroll
    for (int i = 0; i < 4; ++i) {
      av[i] = *reinterpret_cast<const bf16x8*>(
          &sA[cur][(wr * 64 + i * 16 + (lane & 15)) * 32 + (lane >> 4) * 8]);
      bv[i] = *reinterpret_cast<const bf16x8*>(
          &sB[cur][(wc * 64 + i * 16 + (lane & 15)) * 32 + (lane >> 4) * 8]);
    }
#pragma unroll
    for (int mi = 0; mi < 4; ++mi)
#pragma unroll
      for (int ni = 0; ni < 4; ++ni)
        acc[mi][ni] = __builtin_amdgcn_mfma_f32_16x16x32_bf16(av[mi], bv[ni], acc[mi][ni], 0, 0, 0);
    __syncthreads();                  // drains vmcnt -> next buffer ready
    cur ^= 1;
  }

  if constexpr (EPI == EPI_QKV) {
    const int sect = n0 >> 10;        // 0=Q 1=K 2=V
#pragma unroll
    for (int ni = 0; ni < 4; ++ni) {
      const int col = n0 + wc * 64 + ni * 16 + (lane & 15);
      const int c10 = col & 1023;
      float bvs = 0.0f;
      if (sect == 0) bvs = bias[c10];
      else if (sect == 2) bvs = bias2[c10];
#pragma unroll
      for (int mi = 0; mi < 4; ++mi) {
#pragma unroll
        for (int r = 0; r < 4; ++r) {
          const int row = m0 + wr * 64 + mi * 16 + (lane >> 4) * 4 + r;
          const int s = row & 1023;
          float val = acc[mi][ni][r] + bvs;
          if (sect < 2) {             // rope + scale (table pre-scaled)
            const float2 t = rtab[(s << 6) + ((col & 127) >> 1)];
            const float p = __shfl_xor(val, 1);
            val = val * t.x + p * ((col & 1) ? t.y : -t.y);
            bf16_t* dst = sect ? out2 : (bf16_t*)Cv;
            dst[(long)row * 1024 + c10] = (bf16_t)val;
          } else {                    // vt[b][h*128+d][s]
            out3[((long)(row >> 10) << 20) + ((long)(col - 2048) << 10) + s] = (bf16_t)val;
          }
        }
      }
    }
    return;
  }

#pragma unroll
  for (int ni = 0; ni < 4; ++ni) {
    const int col = n0 + wc * 64 + ni * 16 + (lane & 15);
    const float bvs = bias ? bias[col] : 0.0f;
#pragma unroll
    for (int mi = 0; mi < 4; ++mi) {
#pragma unroll
      for (int r = 0; r < 4; ++r) {
        const int row = m0 + wr * 64 + mi * 16 + (lane >> 4) * 4 + r;
        float v = acc[mi][ni][r] + bvs;
        if constexpr (EPI == EPI_BF16) {
          ((bf16_t*)Cv)[offC + (long)row * ldc + col] = (bf16_t)v;
        } else if constexpr (EPI == EPI_GELU_BF16) {
          ((bf16_t*)Cv)[offC + (long)row * ldc + col] = (bf16_t)gelu_f(v);
        } else if constexpr (EPI == EPI_GELU_F32) {
          ((float*)Cv)[offC + (long)row * ldc + col] = gelu_f(v);
        } else {  // EPI_RES_F32
          const long idx = offC + (long)row * ldc + col;
          ((float*)Cv)[idx] = res[idx] + v;
        }
      }
    }
  }
}

// LayerNorm: one block per row of 1024 f32 -> bf16
__global__ __launch_bounds__(256)
void ln_kernel(const float* __restrict__ x, bf16_t* __restrict__ y,
               const float* __restrict__ w, const float* __restrict__ b)
{
  const long row = blockIdx.x;
  const float4 v = reinterpret_cast<const float4*>(x + row * ND)[threadIdx.x];
  float s  = v.x + v.y + v.z + v.w;
  float ss = v.x * v.x + v.y * v.y + v.z * v.z + v.w * v.w;
#pragma unroll
  for (int off = 32; off; off >>= 1) { s += __shfl_down(s, off); ss += __shfl_down(ss, off); }
  __shared__ float sh[8];
  if ((threadIdx.x & 63) == 0) { sh[threadIdx.x >> 6] = s; sh[4 + (threadIdx.x >> 6)] = ss; }
  __syncthreads();
  const float tot  = sh[0] + sh[1] + sh[2] + sh[3];
  const float tot2 = sh[4] + sh[5] + sh[6] + sh[7];
  const float mean = tot * (1.0f / ND);
  const float var  = tot2 * (1.0f / ND) - mean * mean;
  const float rstd = rsqrtf(var + 1e-5f);
  const int i0 = threadIdx.x * 4;
  const float vv[4] = {v.x, v.y, v.z, v.w};
  bf16x4 o;
#pragma unroll
  for (int j = 0; j < 4; ++j)
    o[j] = (bf16_t)((vv[j] - mean) * rstd * w[i0 + j] + b[i0 + j]);
  reinterpret_cast<bf16x4*>(y + row * ND)[threadIdx.x] = o;
}

// masked softmax over one score row (1024), in place, bf16.
// rows cover `nb` batches: row = (b_rel*8 + h)*1024 + q
__global__ __launch_bounds__(256)
void softmax_kernel(bf16_t* __restrict__ p, const float* __restrict__ validb)
{
  const long row = blockIdx.x;
  const int b_rel = (int)(row >> 13);
  bf16_t* pr = p + row * (long)NS;
  const float* vb = validb + (long)b_rel * NS;
  const int i0 = threadIdx.x * 4;
  bf16x4 raw = reinterpret_cast<const bf16x4*>(pr)[threadIdx.x];
  float sv[4]; float mx = -3e38f;
#pragma unroll
  for (int j = 0; j < 4; ++j) {
    float s = (vb[i0 + j] != 0.0f) ? (float)raw[j] : -3e38f;
    sv[j] = s; mx = fmaxf(mx, s);
  }
#pragma unroll
  for (int off = 32; off; off >>= 1) mx = fmaxf(mx, __shfl_down(mx, off));
  __shared__ float sh[4];
  if ((threadIdx.x & 63) == 0) sh[threadIdx.x >> 6] = mx;
  __syncthreads();
  mx = fmaxf(fmaxf(sh[0], sh[1]), fmaxf(sh[2], sh[3]));
  __syncthreads();
  float sum = 0.0f;
#pragma unroll
  for (int j = 0; j < 4; ++j) {
    float e = (sv[j] > -1e37f) ? __expf(sv[j] - mx) : 0.0f;
    sv[j] = e; sum += e;
  }
#pragma unroll
  for (int off = 32; off; off >>= 1) sum += __shfl_down(sum, off);
  if ((threadIdx.x & 63) == 0) sh[threadIdx.x >> 6] = sum;
  __syncthreads();
  sum = sh[0] + sh[1] + sh[2] + sh[3];
  const float inv = 1.0f / sum;
  bf16x4 o;
#pragma unroll
  for (int j = 0; j < 4; ++j) o[j] = (bf16_t)(sv[j] * inv);
  reinterpret_cast<bf16x4*>(pr)[threadIdx.x] = o;
}

// pre-scaled rope table: rtab[s*64+i] = (cos(s*f_i), sin(s*f_i)) * 128^-0.25
__global__ __launch_bounds__(256)
void rtab_kernel(float2* __restrict__ tab)
{
  const int idx = blockIdx.x * 256 + threadIdx.x;   // 65536
  const int s = idx >> 6, i = idx & 63;
  const float freq = __expf((float)i * -0.14391156831212787f);  // 10000^(-2i/128)
  float sn, cs;
  sincosf((float)s * freq, &sn, &cs);
  const float sc = 0.29730177875068026f;
  tab[idx] = make_float2(cs * sc, sn * sc);
}

// im2col conv1: A1[(b*2048+t), i*3+kk] = x[b, i, 2t+kk-1] (pad 1), f32->bf16
__global__ __launch_bounds__(256)
void im2col1_kernel(const float* __restrict__ x, bf16_t* __restrict__ a)
{
  const long idx = (long)blockIdx.x * 256 + threadIdx.x;
  if (idx >= (long)NB * NT1 * 384) return;
  const int  k = (int)(idx % 384);
  const long m = idx / 384;
  const int i = k / 3, kk = k - 3 * i;
  const int t = (int)(m & (NT1 - 1));
  const int b = (int)(m >> 11);
  const int tt = 2 * t + kk - 1;
  float v = 0.0f;
  if (tt >= 0 && tt < NT) v = x[((long)b * 128 + i) * NT + tt];
  a[idx] = (bf16_t)v;
}

// im2col conv2: A2[(b*1024+t), i*3+kk] = h1[b, 2t+kk-1, i] (pad 1)
__global__ __launch_bounds__(256)
void im2col2_kernel(const bf16_t* __restrict__ h1, bf16_t* __restrict__ a)
{
  const long idx = (long)blockIdx.x * 256 + threadIdx.x;
  if (idx >= (long)NB * NS * 3072) return;
  const int  k = (int)(idx % 3072);
  const long m = idx / 3072;
  const int i = k / 3, kk = k - 3 * i;
  const int t = (int)(m & (NS - 1));
  const int b = (int)(m >> 10);
  const int tt = 2 * t + kk - 1;
  bf16_t v = (bf16_t)0.0f;
  if (tt >= 0 && tt < NT1) v = h1[((long)b * NT1 + tt) * ND + i];
  a[idx] = v;
}

__global__ __launch_bounds__(256)
void mask_kernel(const int* __restrict__ xlen, float* __restrict__ valid)
{
  const int idx = blockIdx.x * 256 + threadIdx.x;
  if (idx >= NB * NS) return;
  const int b = idx >> 10, j = idx & 1023;
  valid[idx] = (4 * j + 3 < xlen[b]) ? 1.0f : 0.0f;
}

__global__ void ylen_kernel(const int* __restrict__ xlen, float* __restrict__ ylen)
{
  const int b = threadIdx.x;
  if (b < NB) {
    const int y1 = (xlen[b] + 1) >> 1;
    ylen[b] = (float)((y1 + 1) >> 1);
  }
}

__global__ __launch_bounds__(256)
void cvt_kernel(const float* __restrict__ in, bf16_t* __restrict__ out, long n)
{
  const long i = ((long)blockIdx.x * 256 + threadIdx.x) * 4;
  if (i >= n) return;
  const float4 v = *reinterpret_cast<const float4*>(in + i);
  bf16x4 o;
  o[0] = (bf16_t)v.x; o[1] = (bf16_t)v.y; o[2] = (bf16_t)v.z; o[3] = (bf16_t)v.w;
  *reinterpret_cast<bf16x4*>(out + i) = o;
}

extern "C" void kernel_launch(void* const* d_in, const int* in_sizes, int n_in,
                              void* d_out, int out_size, void* d_ws, size_t ws_size,
                              hipStream_t stream)
{
  const float* x         = (const float*)d_in[0];
  const int*   x_len     = (const int*)  d_in[1];
  const float* conv1_w   = (const float*)d_in[2];
  const float* conv1_b   = (const float*)d_in[3];
  const float* conv2_w   = (const float*)d_in[4];
  const float* conv2_b   = (const float*)d_in[5];
  const float* attn_ln_w = (const float*)d_in[6];
  const float* attn_ln_b = (const float*)d_in[7];
  const float* q_w   = (const float*)d_in[8];
  const float* q_b   = (const float*)d_in[9];
  const float* k_w   = (const float*)d_in[10];
  const float* v_w   = (const float*)d_in[11];
  const float* v_b   = (const float*)d_in[12];
  const float* out_w = (const float*)d_in[13];
  const float* out_b = (const float*)d_in[14];
  const float* mlp_ln_w = (const float*)d_in[15];
  const float* mlp_ln_b = (const float*)d_in[16];
  const float* mlp1_w = (const float*)d_in[17];
  const float* mlp1_b = (const float*)d_in[18];
  const float* mlp2_w = (const float*)d_in[19];
  const float* mlp2_b = (const float*)d_in[20];
  float* outp = (float*)d_out;
  (void)in_sizes; (void)n_in; (void)out_size;

  const long MB = 1024L * 1024;
  // ---- workspace (~120 MB) ----
  char* ws = (char*)d_ws;
  size_t off = 0;
  auto alloc = [&](size_t bytes) -> char* {
    char* p = ws + off;
    off += (bytes + 255) & ~(size_t)255;
    return p;
  };
  float*  valid = (float*) alloc(NB * NS * 4);   //  32 KB
  bf16_t* ybuf  = (bf16_t*)alloc(16 * MB);       //  16 MB | a1(conv)    | kbuf? no: ln out
  bf16_t* qbuf  = (bf16_t*)alloc(16 * MB);       //  16 MB | h1[0:16]    | Q then O
  char*   R     = alloc(64 * MB);                //  64 MB | h1[16:32]+a2 | kbuf+scb | hid
  char*   wA    = alloc(24 * MB);                //  24 MB | weights/vt/rtab
  const size_t required = off;

  // conv-phase aliases
  bf16_t* a1  = ybuf;                            // 12 MB
  bf16_t* h1  = qbuf;                            // 32 MB (qbuf + R[0:16])
  bf16_t* a2  = (bf16_t*)(R + 16 * MB);          // 48 MB
  bf16_t* c2w = (bf16_t*)wA;                     //  6 MB
  bf16_t* c1w = (bf16_t*)(wA + 8 * MB);          // 0.75 MB
  // persistent
  float2* rtab = (float2*)(wA + 6 * MB);         // 512 KB, [6:6.5], never clobbered
  // layer-phase aliases
  bf16_t* wqkv = (bf16_t*)wA;                    // [0:6]  q,k,v weights
  bf16_t* vt   = (bf16_t*)(wA + 8 * MB);         // [8:24] during attention
  bf16_t* wo   = (bf16_t*)(wA + 16 * MB);        // [16:18] after PV (vt dead)
  bf16_t* w1b  = (bf16_t*)(wA + 8 * MB);         // [8:16] after attn-out
  bf16_t* w2b  = (bf16_t*)(wA + 16 * MB);        // [16:24]
  bf16_t* kbuf = (bf16_t*)R;                     // [0:16] during attention
  bf16_t* scb  = (bf16_t*)(R + 16 * MB);         // [16:64] 3-batch scores
  bf16_t* hid  = (bf16_t*)R;                     // 64 MB during MLP

  if (required > ws_size) {
    ylen_kernel<<<dim3(1), 64, 0, stream>>>(x_len, outp + 8L * 1024 * 1024);
    return;
  }

  auto cvt = [&](const float* in, bf16_t* o, long n) {
    cvt_kernel<<<dim3((unsigned)(n / 1024)), 256, 0, stream>>>(in, o, n);
  };

  mask_kernel<<<dim3(32), 256, 0, stream>>>(x_len, valid);
  rtab_kernel<<<dim3(256), 256, 0, stream>>>(rtab);

  // ---- conv stem ----
  cvt(conv1_w, c1w, 1024L * 384);
  cvt(conv2_w, c2w, 1024L * 3072);
  im2col1_kernel<<<dim3((unsigned)((16384L * 384) / 256)), 256, 0, stream>>>(x, a1);
  gemm_bt<EPI_GELU_BF16><<<dim3(128, 8, 1), 256, 0, stream>>>(
      a1, 384, 0, 0, c1w, 384, 0, 0, h1, 1024, 0, 0, conv1_b, nullptr, 384, 1, 1,
      nullptr, nullptr, nullptr, nullptr);
  im2col2_kernel<<<dim3((unsigned)((8192L * 3072) / 256)), 256, 0, stream>>>(h1, a2);
  gemm_bt<EPI_GELU_F32><<<dim3(64, 8, 1), 256, 0, stream>>>(
      a2, 3072, 0, 0, c2w, 3072, 0, 0, outp /*carry*/, 1024, 0, 0, conv2_b, nullptr, 3072, 1, 1,
      nullptr, nullptr, nullptr, nullptr);

  float* carry = outp;  // f32 residual stream lives in d_out

  for (int l = 0; l < 6; ++l) {
    cvt(q_w + (long)l * 1048576, wqkv,            1048576);
    cvt(k_w + (long)l * 1048576, wqkv + 1048576,  1048576);
    cvt(v_w + (long)l * 1048576, wqkv + 2097152,  1048576);

    ln_kernel<<<dim3(8192), 256, 0, stream>>>(carry, ybuf, attn_ln_w + l * 1024, attn_ln_b + l * 1024);

    // fused QKV projection + rope/scale + V-transpose (N=3072)
    gemm_bt<EPI_QKV><<<dim3(64, 24, 1), 256, 0, stream>>>(
        ybuf, 1024, 0, 0, wqkv, 1024, 0, 0, qbuf, 1024, 0, 0,
        q_b + l * 1024, nullptr, 1024, 1, 1, kbuf, vt, v_b + l * 1024, rtab);

    // attention, 3-batch chunks (scores in 48 MB scb)
    for (int b0 = 0; b0 < NB; b0 += 3) {
      const int nb = (NB - b0) < 3 ? (NB - b0) : 3;
      gemm_bt<EPI_BF16><<<dim3(8, 8, nb * 8), 256, 0, stream>>>(
          qbuf + (long)b0 * 1048576, 1024, 1048576, 128,
          kbuf + (long)b0 * 1048576, 1024, 1048576, 128,
          scb, 1024, 8388608, 1048576, nullptr, nullptr, 128, 8, 0,
          nullptr, nullptr, nullptr, nullptr);
      softmax_kernel<<<dim3(nb * 8192), 256, 0, stream>>>(scb, valid + (long)b0 * NS);
      gemm_bt<EPI_BF16><<<dim3(8, 1, nb * 8), 256, 0, stream>>>(
          scb, 1024, 8388608, 1048576,
          vt + (long)b0 * 1048576, 1024, 1048576, 131072,
          qbuf + (long)b0 * 1048576 /*obuf in place*/, 1024, 1048576, 128,
          nullptr, nullptr, 1024, 8, 0, nullptr, nullptr, nullptr, nullptr);
    }

    // carry += O @ ow^T + ob
    cvt(out_w + (long)l * 1048576, wo, 1048576);
    gemm_bt<EPI_RES_F32><<<dim3(64, 8, 1), 256, 0, stream>>>(
        qbuf, 1024, 0, 0, wo, 1024, 0, 0, carry, 1024, 0, 0,
        out_b + l * 1024, carry, 1024, 1, 1, nullptr, nullptr, nullptr, nullptr);

    cvt(mlp1_w + (long)l * 4194304, w1b, 4194304);
    cvt(mlp2_w + (long)l * 4194304, w2b, 4194304);

    ln_kernel<<<dim3(8192), 256, 0, stream>>>(carry, ybuf, mlp_ln_w + l * 1024, mlp_ln_b + l * 1024);

    // hid = gelu(y @ w1^T + b1)   (full N=4096)
    gemm_bt<EPI_GELU_BF16><<<dim3(64, 32, 1), 256, 0, stream>>>(
        ybuf, 1024, 0, 0, w1b, 1024, 0, 0, hid, 4096, 0, 0,
        mlp1_b + (long)l * 4096, nullptr, 1024, 1, 1, nullptr, nullptr, nullptr, nullptr);
    // carry += hid @ w2^T + b2   (full K=4096)
    gemm_bt<EPI_RES_F32><<<dim3(64, 8, 1), 256, 0, stream>>>(
        hid, 4096, 0, 0, w2b, 4096, 0, 0, carry, 1024, 0, 0,
        mlp2_b + l * 1024, carry, 4096, 1, 1, nullptr, nullptr, nullptr, nullptr);
  }

  ylen_kernel<<<dim3(1), 64, 0, stream>>>(x_len, outp + 8L * 1024 * 1024);
}